// Round 8
// baseline (294.470 us; speedup 1.0000x reference)
//
#include <hip/hip_runtime.h>
#include <math.h>

#define Bsz 4096
#define Dk 128
#define RPB 32                   // rows per block / per group
#define COL_SPLIT 8
#define CPB (Bsz / COL_SPLIT)    // 512 cols per block
#define THREADS 256
#define WAVES 4
#define CPW (CPB / WAVES)        // 128 cols per wave
#define CT (CPW / 16)            // 8 col-tiles per wave
#define RT (RPB / 16)            // 2 row-tiles
#define LDSW 520                 // padded LDS row (1040 B, 16B-aligned)
#define NGRP (Bsz / RPB)         // 128 row-groups
// cells layout (u64): [0..127]=grp counters, [128..143]=loss fx, [144..159]=cnt, [160]=done
#define NCELLS 161
#define FXS 1099511627776.0      // 2^40 fixed-point scale

typedef __attribute__((ext_vector_type(8))) short short8;
typedef __attribute__((ext_vector_type(4))) float f32x4;
typedef _Float16 half8 __attribute__((ext_vector_type(8)));

__device__ __forceinline__ unsigned short f2bf(float f) {
  unsigned u = __float_as_uint(f);
  u = (u + 0x7fffu + ((u >> 16) & 1u)) >> 16;   // RNE
  return (unsigned short)u;
}

// X fp32 -> bf16; zero the atomic cells (required every launch: counters/sums
// accumulate and ws is never re-poisoned between replays).
__global__ __launch_bounds__(256)
void convert_kernel(const float* __restrict__ X, short* __restrict__ Xb,
                    unsigned long long* __restrict__ cells) {
  int i = blockIdx.x * 256 + threadIdx.x;     // 65536 threads x 8 elems
  if (i < NCELLS) cells[i] = 0ull;
  const float4* q = (const float4*)X + i * 2;
  float4 v0 = q[0], v1 = q[1];
  short8 r;
  r[0] = (short)f2bf(v0.x); r[1] = (short)f2bf(v0.y);
  r[2] = (short)f2bf(v0.z); r[3] = (short)f2bf(v0.w);
  r[4] = (short)f2bf(v1.x); r[5] = (short)f2bf(v1.y);
  r[6] = (short)f2bf(v1.z); r[7] = (short)f2bf(v1.w);
  ((short8*)Xb)[i] = r;
}

// One kernel: GEMM -> enc-sim (self->8, eq->sim+4, else sim) NT-stored to
// global + per-row min/max partials; then per-group done-counter: the 8th
// column-split to finish a 32-row group becomes its "finisher" and runs the
// exp/log1p phase for those rows immediately (split-K-reduction pattern).
// Final mean via exact fixed-point atomics + grid done counter.
__global__ __launch_bounds__(THREADS, 4)
void fused(const short* __restrict__ Xb, const int* __restrict__ labels,
           _Float16* __restrict__ sim16,
           float* __restrict__ min_part, float* __restrict__ max_part,
           unsigned long long* __restrict__ cells, float* __restrict__ out) {
  const int tid = threadIdx.x;
  const int w  = tid >> 6;
  const int l  = tid & 63;
  const int lg = l >> 4;     // k-group / C row-group
  const int lr = l & 15;     // A row-in-tile / B,C col-in-tile
  const int by = blockIdx.x >> 3;   // row-group: 8 consecutive bids = 8 splits (8 XCDs)
  const int bx = blockIdx.x & 7;
  const int r0 = by * RPB;
  const int c0 = bx * CPB + w * CPW;

  __shared__ __align__(16) _Float16 tile[RPB][LDSW];   // 33,280 B
  __shared__ float red[2][WAVES][RPB];

  // ---- GEMM: 32 rows x 512 cols ----
  short8 afrag[RT][4];
  for (int rt = 0; rt < RT; ++rt) {
    int row = r0 + rt * 16 + lr;
    for (int ks = 0; ks < 4; ++ks)
      afrag[rt][ks] = *(const short8*)(Xb + row * Dk + ks * 32 + lg * 8);
  }
  int labr[RT * 4];
  for (int rt = 0; rt < RT; ++rt)
    for (int rg = 0; rg < 4; ++rg)
      labr[rt * 4 + rg] = labels[r0 + rt * 16 + lg * 4 + rg];

  float mn[RT * 4], mx[RT * 4];
  for (int i = 0; i < RT * 4; ++i) { mn[i] = INFINITY; mx[i] = -INFINITY; }

  for (int ct = 0; ct < CT; ++ct) {
    const int ctc  = c0 + ct * 16;
    const int colv = ctc + lr;
    short8 bfrag[4];
    for (int ks = 0; ks < 4; ++ks)
      bfrag[ks] = *(const short8*)(Xb + colv * Dk + ks * 32 + lg * 8);
    const int labc = labels[colv];

    for (int rt = 0; rt < RT; ++rt) {
      f32x4 acc = {0.f, 0.f, 0.f, 0.f};
      for (int ks = 0; ks < 4; ++ks)
        acc = __builtin_amdgcn_mfma_f32_16x16x32_bf16(afrag[rt][ks], bfrag[ks], acc, 0, 0, 0);
      const bool diag = (ctc == r0 + rt * 16);   // wave-uniform
      const int  lcol = w * CPW + ct * 16 + lr;
      // C/D layout (verified): col = lane&15, row = (lane>>4)*4 + reg
      for (int rg = 0; rg < 4; ++rg) {
        int   i    = rt * 4 + rg;
        float s    = acc[rg];
        bool  eq   = (labc == labr[i]);
        bool  self = diag && (lr == lg * 4 + rg);
        if (eq && !self) mn[i] = fminf(mn[i], s);
        if (!eq)         mx[i] = fmaxf(mx[i], s);
        float enc = eq ? s + 4.0f : s;
        if (self) enc = 8.0f;
        tile[rt * 16 + lg * 4 + rg][lcol] = (_Float16)enc;
      }
    }
  }

  // min/max across the 16 col-lanes sharing each row
  for (int i = 0; i < RT * 4; ++i) {
    for (int m = 1; m < 16; m <<= 1) {
      mn[i] = fminf(mn[i], __shfl_xor(mn[i], m, 64));
      mx[i] = fmaxf(mx[i], __shfl_xor(mx[i], m, 64));
    }
  }
  if (lr == 0)
    for (int i = 0; i < RT * 4; ++i) {
      int rt = i >> 2, rg = i & 3;
      red[0][w][rt * 16 + lg * 4 + rg] = mn[i];
      red[1][w][rt * 16 + lg * 4 + rg] = mx[i];
    }
  __syncthreads();

  if (tid < RPB) {
    float v0 = INFINITY, v1 = -INFINITY;
    for (int ww = 0; ww < WAVES; ++ww) {
      v0 = fminf(v0, red[0][ww][tid]);
      v1 = fmaxf(v1, red[1][ww][tid]);
    }
    min_part[bx * Bsz + r0 + tid] = v0;
    max_part[bx * Bsz + r0 + tid] = v1;
  }

  // coalesced NT store of the enc tile (row-major, 1KB contiguous per row;
  // NT: skip L2 so Xb stays resident, data lands in L3 for the finisher)
  for (int k = 0; k < RPB / WAVES; ++k) {
    int rr = w * (RPB / WAVES) + k;
    f32x4 v = *(const f32x4*)&tile[rr][l * 8];
    __builtin_nontemporal_store(v, (f32x4*)(sim16 + (size_t)(r0 + rr) * Bsz + bx * CPB + l * 8));
  }

  // ---- group done-counter: 8th arriver runs phase 2 for this group ----
  __threadfence();   // release: sim + partial stores visible before increment
  __shared__ int amF;
  if (tid == 0) amF = (atomicAdd(&cells[by], 1ull) == (unsigned long long)(COL_SPLIT - 1));
  __syncthreads();
  if (!amF) return;
  __threadfence();   // acquire: see all 8 splits' data

  __shared__ float thp_s[RPB], thn_s[RPB], vld_s[RPB];
  __shared__ float ls[WAVES], cs[WAVES];
  if (tid < RPB) {
    int r = r0 + tid;
    float mnr = INFINITY, mxr = -INFINITY;
    for (int b = 0; b < COL_SPLIT; ++b) {
      mnr = fminf(mnr, min_part[b * Bsz + r]);
      mxr = fmaxf(mxr, max_part[b * Bsz + r]);
    }
    thp_s[tid] = mxr + 4.1f;                  // pos_keep: v=s+4 < max_neg+4.1
    thn_s[tid] = mnr - 0.1f;                  // neg_keep: v=s > min_pos-0.1
    vld_s[tid] = (mnr - 0.1f < mxr) ? 1.f : 0.f;
  }
  __syncthreads();

  float wl = 0.f, wc = 0.f;                   // per-wave loss/count (lane 0)
  for (int k = 0; k < RPB / WAVES; ++k) {
    const int rr = w * (RPB / WAVES) + k;
    const float tp = thp_s[rr], tn = thn_s[rr];
    const half8* bp = (const half8*)(sim16 + (size_t)(r0 + rr) * Bsz);
    float ap = 0.f, an = 0.f;
#pragma unroll
    for (int q = 0; q < 8; ++q) {
      half8 h = bp[l + q * 64];
#pragma unroll
      for (int j = 0; j < 8; ++j) {
        float v  = (float)h[j];
        bool  eq = v > 2.0f;
        bool  kp = eq && (v < tp);            // self v=8 >= tp(<=5.1) -> excluded
        bool  kn = !eq && (v > tn);
        float argp = fmaf(v, -2.885390082f, 12.98425537f);   // -2*(v-4.5)*log2e
        float argn = fmaf(v, 57.70780163f, -28.85390082f);   // 40*(v-0.5)*log2e
        float e = exp2f(kp ? argp : argn);
        ap += kp ? e : 0.f;
        an += kn ? e : 0.f;
      }
    }
    for (int m = 1; m < 64; m <<= 1) {
      ap += __shfl_xor(ap, m, 64);
      an += __shfl_xor(an, m, 64);
    }
    if (l == 0 && vld_s[rr] > 0.f) {
      wl += log1pf(ap) * 0.5f + log1pf(an) * 0.025f;
      wc += 1.f;
    }
  }
  if (l == 0) { ls[w] = wl; cs[w] = wc; }
  __syncthreads();

  if (tid == 0) {
    float L = 0.f, C = 0.f;
    for (int ww = 0; ww < WAVES; ++ww) { L += ls[ww]; C += cs[ww]; }
    atomicAdd(&cells[128 + (by & 15)], (unsigned long long)(long long)((double)L * FXS));
    atomicAdd(&cells[144 + (by & 15)], (unsigned long long)(int)C);
    __threadfence();
    if (atomicAdd(&cells[160], 1ull) == (unsigned long long)(NGRP - 1)) {
      unsigned long long S = 0ull, C2 = 0ull;
      for (int i = 0; i < 16; ++i) {
        S  += atomicAdd(&cells[128 + i], 0ull);
        C2 += atomicAdd(&cells[144 + i], 0ull);
      }
      out[0] = (float)((double)(long long)S / FXS / (double)(C2 ? C2 : 1ull));
    }
  }
}

extern "C" void kernel_launch(void* const* d_in, const int* in_sizes, int n_in,
                              void* d_out, int out_size, void* d_ws, size_t ws_size,
                              hipStream_t stream) {
  const float* X      = (const float*)d_in[0];
  const int*   labels = (const int*)d_in[1];

  char* ws = (char*)d_ws;
  _Float16*           sim16    = (_Float16*)(ws);                             // 32 MB
  short*              Xb       = (short*)(ws + 33554432);                     // 1 MB
  float*              min_part = (float*)(ws + 33554432 + 1048576);           // 128 KB
  float*              max_part = (float*)(ws + 33554432 + 1048576 + 131072);  // 128 KB
  unsigned long long* cells    = (unsigned long long*)(ws + 33554432 + 1048576 + 262144);

  convert_kernel<<<256, 256, 0, stream>>>(X, Xb, cells);
  fused<<<NGRP * COL_SPLIT, THREADS, 0, stream>>>(Xb, labels, sim16, min_part, max_part, cells, (float*)d_out);
}

// Round 9
// 61.486 us; speedup vs baseline: 4.7892x; 4.7892x over previous
//
#include <hip/hip_runtime.h>
#include <math.h>

#define Bsz 4096
#define Dk 128
#define RPB 32                   // rows per block
#define COL_SPLIT 8
#define CPB (Bsz / COL_SPLIT)    // 512 cols per block
#define THREADS 256
#define WAVES 4
#define CPW (CPB / WAVES)        // 128 cols per wave
#define CT (CPW / 16)            // 8 col-tiles per wave
#define RT (RPB / 16)            // 2 row-tiles

typedef __attribute__((ext_vector_type(8))) short short8;
typedef __attribute__((ext_vector_type(4))) float f32x4;

__device__ __forceinline__ unsigned short f2bf(float f) {
  unsigned u = __float_as_uint(f);
  u = (u + 0x7fffu + ((u >> 16) & 1u)) >> 16;   // RNE
  return (unsigned short)u;
}

// X fp32 [4096][128] -> bf16 [4096][128]
__global__ __launch_bounds__(256)
void convert_kernel(const float* __restrict__ X, short* __restrict__ Xb) {
  int i = blockIdx.x * 256 + threadIdx.x;     // 65536 threads x 8 elems
  const float4* q = (const float4*)X + i * 2;
  float4 v0 = q[0], v1 = q[1];
  short8 r;
  r[0] = (short)f2bf(v0.x); r[1] = (short)f2bf(v0.y);
  r[2] = (short)f2bf(v0.z); r[3] = (short)f2bf(v0.w);
  r[4] = (short)f2bf(v1.x); r[5] = (short)f2bf(v1.y);
  r[6] = (short)f2bf(v1.z); r[7] = (short)f2bf(v1.w);
  ((short8*)Xb)[i] = r;
}

// Pass 1: GEMM -> per-row masked min(pos)/max(neg) partials. NO sim storage.
__global__ __launch_bounds__(THREADS, 4)
void pass1(const short* __restrict__ Xb, const int* __restrict__ labels,
           float* __restrict__ min_part, float* __restrict__ max_part) {
  const int tid = threadIdx.x;
  const int w  = tid >> 6;
  const int l  = tid & 63;
  const int lg = l >> 4;     // k-group / C row-group
  const int lr = l & 15;     // A row-in-tile / B,C col-in-tile
  const int by = blockIdx.x / COL_SPLIT;
  const int bx = blockIdx.x % COL_SPLIT;
  const int r0 = by * RPB;
  const int c0 = bx * CPB + w * CPW;

  __shared__ float red[2][WAVES][RPB];

  short8 afrag[RT][4];
  for (int rt = 0; rt < RT; ++rt) {
    int row = r0 + rt * 16 + lr;
    for (int ks = 0; ks < 4; ++ks)
      afrag[rt][ks] = *(const short8*)(Xb + row * Dk + ks * 32 + lg * 8);
  }
  int labr[RT * 4];
  for (int rt = 0; rt < RT; ++rt)
    for (int rg = 0; rg < 4; ++rg)
      labr[rt * 4 + rg] = labels[r0 + rt * 16 + lg * 4 + rg];

  float mn[RT * 4], mx[RT * 4];
  for (int i = 0; i < RT * 4; ++i) { mn[i] = INFINITY; mx[i] = -INFINITY; }

  for (int ct = 0; ct < CT; ++ct) {
    const int ctc  = c0 + ct * 16;
    const int colv = ctc + lr;
    short8 bfrag[4];
    for (int ks = 0; ks < 4; ++ks)
      bfrag[ks] = *(const short8*)(Xb + colv * Dk + ks * 32 + lg * 8);
    const int labc = labels[colv];

    for (int rt = 0; rt < RT; ++rt) {
      f32x4 acc = {0.f, 0.f, 0.f, 0.f};
      for (int ks = 0; ks < 4; ++ks)
        acc = __builtin_amdgcn_mfma_f32_16x16x32_bf16(afrag[rt][ks], bfrag[ks], acc, 0, 0, 0);
      const bool diag = (ctc == r0 + rt * 16);   // wave-uniform
      // C/D layout (verified): col = lane&15, row = (lane>>4)*4 + reg
      for (int rg = 0; rg < 4; ++rg) {
        int   i    = rt * 4 + rg;
        float s    = acc[rg];
        bool  eq   = (labc == labr[i]);
        bool  self = diag && (lr == lg * 4 + rg);
        if (eq && !self) mn[i] = fminf(mn[i], s);
        if (!eq)         mx[i] = fmaxf(mx[i], s);
      }
    }
  }

  for (int i = 0; i < RT * 4; ++i) {
    for (int m = 1; m < 16; m <<= 1) {
      mn[i] = fminf(mn[i], __shfl_xor(mn[i], m, 64));
      mx[i] = fmaxf(mx[i], __shfl_xor(mx[i], m, 64));
    }
  }
  if (lr == 0)
    for (int i = 0; i < RT * 4; ++i) {
      int rt = i >> 2, rg = i & 3;
      red[0][w][rt * 16 + lg * 4 + rg] = mn[i];
      red[1][w][rt * 16 + lg * 4 + rg] = mx[i];
    }
  __syncthreads();

  if (tid < RPB) {
    float v0 = INFINITY, v1 = -INFINITY;
    for (int ww = 0; ww < WAVES; ++ww) {
      v0 = fminf(v0, red[0][ww][tid]);
      v1 = fmaxf(v1, red[1][ww][tid]);
    }
    min_part[bx * Bsz + r0 + tid] = v0;
    max_part[bx * Bsz + r0 + tid] = v1;
  }
}

// Pass 2: GEMM again -> thresholded exp-sum partials. Thresholds gathered from
// pass1 partials once per block. bx==0 also writes the per-row validity flag.
__global__ __launch_bounds__(THREADS, 4)
void pass2(const short* __restrict__ Xb, const int* __restrict__ labels,
           const float* __restrict__ min_part, const float* __restrict__ max_part,
           float* __restrict__ pos_part, float* __restrict__ neg_part,
           float* __restrict__ vld) {
  const int tid = threadIdx.x;
  const int w  = tid >> 6;
  const int l  = tid & 63;
  const int lg = l >> 4;
  const int lr = l & 15;
  const int by = blockIdx.x / COL_SPLIT;
  const int bx = blockIdx.x % COL_SPLIT;
  const int r0 = by * RPB;
  const int c0 = bx * CPB + w * CPW;

  __shared__ float red[2][WAVES][RPB];
  __shared__ float thp_s[RPB], thn_s[RPB];

  if (tid < RPB) {
    int r = r0 + tid;
    float mnr = INFINITY, mxr = -INFINITY;
    for (int b = 0; b < COL_SPLIT; ++b) {
      mnr = fminf(mnr, min_part[b * Bsz + r]);
      mxr = fmaxf(mxr, max_part[b * Bsz + r]);
    }
    thp_s[tid] = mxr + 0.1f;    // pos_keep: s < max_neg + 0.1
    thn_s[tid] = mnr - 0.1f;    // neg_keep: s > min_pos - 0.1
    if (bx == 0) vld[r] = (mnr - 0.1f < mxr) ? 1.0f : 0.0f;
  }

  short8 afrag[RT][4];
  for (int rt = 0; rt < RT; ++rt) {
    int row = r0 + rt * 16 + lr;
    for (int ks = 0; ks < 4; ++ks)
      afrag[rt][ks] = *(const short8*)(Xb + row * Dk + ks * 32 + lg * 8);
  }
  int labr[RT * 4];
  for (int rt = 0; rt < RT; ++rt)
    for (int rg = 0; rg < 4; ++rg)
      labr[rt * 4 + rg] = labels[r0 + rt * 16 + lg * 4 + rg];

  __syncthreads();
  float tp[RT * 4], tn[RT * 4];
  for (int rt = 0; rt < RT; ++rt)
    for (int rg = 0; rg < 4; ++rg) {
      int rl = rt * 16 + lg * 4 + rg;
      tp[rt * 4 + rg] = thp_s[rl];
      tn[rt * 4 + rg] = thn_s[rl];
    }

  float ap[RT * 4], an[RT * 4];
  for (int i = 0; i < RT * 4; ++i) { ap[i] = 0.f; an[i] = 0.f; }

  for (int ct = 0; ct < CT; ++ct) {
    const int ctc  = c0 + ct * 16;
    const int colv = ctc + lr;
    short8 bfrag[4];
    for (int ks = 0; ks < 4; ++ks)
      bfrag[ks] = *(const short8*)(Xb + colv * Dk + ks * 32 + lg * 8);
    const int labc = labels[colv];

    for (int rt = 0; rt < RT; ++rt) {
      f32x4 acc = {0.f, 0.f, 0.f, 0.f};
      for (int ks = 0; ks < 4; ++ks)
        acc = __builtin_amdgcn_mfma_f32_16x16x32_bf16(afrag[rt][ks], bfrag[ks], acc, 0, 0, 0);
      const bool diag = (ctc == r0 + rt * 16);
      for (int rg = 0; rg < 4; ++rg) {
        int   i    = rt * 4 + rg;
        float s    = acc[rg];
        bool  eq   = (labc == labr[i]);
        bool  self = diag && (lr == lg * 4 + rg);
        bool  kp   = eq && !self && (s < tp[i]);
        bool  kn   = (!eq) && (s > tn[i]);
        float argp = fmaf(s, -2.885390082f, 1.442695041f);   // -2*(s-0.5)*log2e
        float argn = fmaf(s, 57.70780163f, -28.85390082f);   // 40*(s-0.5)*log2e
        float e = exp2f(kp ? argp : argn);
        ap[i] += kp ? e : 0.f;
        an[i] += kn ? e : 0.f;
      }
    }
  }

  for (int i = 0; i < RT * 4; ++i) {
    for (int m = 1; m < 16; m <<= 1) {
      ap[i] += __shfl_xor(ap[i], m, 64);
      an[i] += __shfl_xor(an[i], m, 64);
    }
  }
  if (lr == 0)
    for (int i = 0; i < RT * 4; ++i) {
      int rt = i >> 2, rg = i & 3;
      red[0][w][rt * 16 + lg * 4 + rg] = ap[i];
      red[1][w][rt * 16 + lg * 4 + rg] = an[i];
    }
  __syncthreads();

  if (tid < RPB) {
    float v0 = 0.f, v1 = 0.f;
    for (int ww = 0; ww < WAVES; ++ww) {
      v0 += red[0][ww][tid];
      v1 += red[1][ww][tid];
    }
    pos_part[bx * Bsz + r0 + tid] = v0;
    neg_part[bx * Bsz + r0 + tid] = v1;
  }
}

__global__ __launch_bounds__(1024)
void finalize(const float* __restrict__ pos_part, const float* __restrict__ neg_part,
              const float* __restrict__ vld, float* __restrict__ out) {
  int tid = threadIdx.x;
  float s = 0.f, c = 0.f;
  for (int r = tid; r < Bsz; r += 1024) {
    float ps = 0.f, ns = 0.f;
    for (int b = 0; b < COL_SPLIT; ++b) {
      ps += pos_part[b * Bsz + r];
      ns += neg_part[b * Bsz + r];
    }
    if (vld[r] > 0.f) {
      s += log1pf(ps) * 0.5f + log1pf(ns) * 0.025f;
      c += 1.f;
    }
  }
  for (int m = 1; m < 64; m <<= 1) {
    s += __shfl_xor(s, m, 64);
    c += __shfl_xor(c, m, 64);
  }
  __shared__ float rs[16], rc[16];
  int w = tid >> 6, lz = tid & 63;
  if (lz == 0) { rs[w] = s; rc[w] = c; }
  __syncthreads();
  if (tid == 0) {
    float ts = 0.f, tc = 0.f;
    for (int i = 0; i < 16; ++i) { ts += rs[i]; tc += rc[i]; }
    out[0] = ts / fmaxf(tc, 1.0f);
  }
}

extern "C" void kernel_launch(void* const* d_in, const int* in_sizes, int n_in,
                              void* d_out, int out_size, void* d_ws, size_t ws_size,
                              hipStream_t stream) {
  const float* X      = (const float*)d_in[0];
  const int*   labels = (const int*)d_in[1];

  char* ws = (char*)d_ws;
  short* Xb       = (short*)ws;                         // 1 MB
  float* min_part = (float*)(ws + 1048576);             // 128 KB
  float* max_part = (float*)(ws + 1048576 + 131072);    // 128 KB
  float* pos_part = (float*)(ws + 1048576 + 262144);    // 128 KB
  float* neg_part = (float*)(ws + 1048576 + 393216);    // 128 KB
  float* vld      = (float*)(ws + 1048576 + 524288);    // 16 KB

  convert_kernel<<<256, 256, 0, stream>>>(X, Xb);
  pass1<<<(Bsz / RPB) * COL_SPLIT, THREADS, 0, stream>>>(Xb, labels, min_part, max_part);
  pass2<<<(Bsz / RPB) * COL_SPLIT, THREADS, 0, stream>>>(Xb, labels, min_part, max_part,
                                                         pos_part, neg_part, vld);
  finalize<<<1, 1024, 0, stream>>>(pos_part, neg_part, vld, (float*)d_out);
}

// Round 10
// 55.095 us; speedup vs baseline: 5.3448x; 1.1160x over previous
//
#include <hip/hip_runtime.h>
#include <math.h>

#define Bsz 4096
#define Dk 128
#define RPB 32                   // rows per block
#define COL_SPLIT 8
#define CPB (Bsz / COL_SPLIT)    // 512 cols per block
#define THREADS 256
#define WAVES 4
#define RT (RPB / 16)            // 2 row-tiles
#define CH 128                   // cols per staged LDS chunk (32 KB)
#define NCH (CPB / CH)           // 4 chunks per block
#define TPC (CH / WAVES / 16)    // 2 col-tiles per wave per chunk

typedef __attribute__((ext_vector_type(8))) short short8;
typedef __attribute__((ext_vector_type(4))) float f32x4;

__device__ __forceinline__ unsigned short f2bf(float f) {
  unsigned u = __float_as_uint(f);
  u = (u + 0x7fffu + ((u >> 16) & 1u)) >> 16;   // RNE
  return (unsigned short)u;
}

// X fp32 [4096][128] -> bf16 [4096][128]
__global__ __launch_bounds__(256)
void convert_kernel(const float* __restrict__ X, short* __restrict__ Xb) {
  int i = blockIdx.x * 256 + threadIdx.x;     // 65536 threads x 8 elems
  const float4* q = (const float4*)X + i * 2;
  float4 v0 = q[0], v1 = q[1];
  short8 r;
  r[0] = (short)f2bf(v0.x); r[1] = (short)f2bf(v0.y);
  r[2] = (short)f2bf(v0.z); r[3] = (short)f2bf(v0.w);
  r[4] = (short)f2bf(v1.x); r[5] = (short)f2bf(v1.y);
  r[6] = (short)f2bf(v1.z); r[7] = (short)f2bf(v1.w);
  ((short8*)Xb)[i] = r;
}

// Shared GEMM-sweep skeleton: B staged through LDS (coalesced global loads,
// XOR-swizzled writes, conflict-free ds_read_b128 fragment reads).
// PHASE 0: min(pos)/max(neg) partials.  PHASE 1: thresholded exp-sum partials.
template<int PHASE>
__global__ __launch_bounds__(THREADS, 4)
void sweep(const short* __restrict__ Xb, const int* __restrict__ labels,
           const float* __restrict__ min_part, const float* __restrict__ max_part,
           float* __restrict__ out0, float* __restrict__ out1,
           float* __restrict__ vld) {
  const int tid = threadIdx.x;
  const int w  = tid >> 6;
  const int l  = tid & 63;
  const int lg = l >> 4;     // k-group / C row-group
  const int lr = l & 15;     // A row-in-tile / B,C col-in-tile
  const int by = blockIdx.x / COL_SPLIT;
  const int bx = blockIdx.x % COL_SPLIT;
  const int r0 = by * RPB;

  __shared__ __align__(16) short bsh[CH * Dk];        // 32 KB staged B chunk
  __shared__ int   lab_sh[CH];
  __shared__ float red[2][WAVES][RPB];
  __shared__ float thp_s[RPB], thn_s[RPB];

  if (PHASE == 1) {
    if (tid < RPB) {
      int r = r0 + tid;
      float mnr = INFINITY, mxr = -INFINITY;
      for (int b = 0; b < COL_SPLIT; ++b) {
        mnr = fminf(mnr, min_part[b * Bsz + r]);
        mxr = fmaxf(mxr, max_part[b * Bsz + r]);
      }
      thp_s[tid] = mxr + 0.1f;    // pos_keep: s < max_neg + 0.1
      thn_s[tid] = mnr - 0.1f;    // neg_keep: s > min_pos - 0.1
      if (bx == 0) vld[r] = (mnr - 0.1f < mxr) ? 1.0f : 0.0f;
    }
  }

  // A fragments: 32 rows x K=128 (one-time gather, 8 instrs)
  short8 afrag[RT][4];
  for (int rt = 0; rt < RT; ++rt) {
    int row = r0 + rt * 16 + lr;
    for (int ks = 0; ks < 4; ++ks)
      afrag[rt][ks] = *(const short8*)(Xb + row * Dk + ks * 32 + lg * 8);
  }
  int labr[RT * 4];
  for (int rt = 0; rt < RT; ++rt)
    for (int rg = 0; rg < 4; ++rg)
      labr[rt * 4 + rg] = labels[r0 + rt * 16 + lg * 4 + rg];

  float tp[RT * 4], tn[RT * 4];
  if (PHASE == 1) {
    __syncthreads();   // thp_s/thn_s ready
    for (int rt = 0; rt < RT; ++rt)
      for (int rg = 0; rg < 4; ++rg) {
        int rl = rt * 16 + lg * 4 + rg;
        tp[rt * 4 + rg] = thp_s[rl];
        tn[rt * 4 + rg] = thn_s[rl];
      }
  }

  float a0[RT * 4], a1[RT * 4];
  for (int i = 0; i < RT * 4; ++i) {
    a0[i] = (PHASE == 0) ? INFINITY  : 0.f;
    a1[i] = (PHASE == 0) ? -INFINITY : 0.f;
  }

  for (int ch = 0; ch < NCH; ++ch) {
    const int cb = bx * CPB + ch * CH;       // chunk base col
    // ---- stage: 256 thr x 8 rounds x 16 B, coalesced; XOR-swizzled LDS ----
    {
      const short* src = Xb + cb * Dk;
      for (int r = 0; r < 8; ++r) {
        int soff = r * 2048 + tid * 8;       // shorts
        int byteoff = soff * 2;
        int col = soff >> 7;                 // 128 shorts/col
        int swz = byteoff ^ ((col & 7) << 4);
        *(short8*)((char*)bsh + swz) = *(const short8*)(src + soff);
      }
      if (tid < CH / 4) ((int4*)lab_sh)[tid] = ((const int4*)(labels + cb))[tid];
    }
    __syncthreads();

    // ---- compute: each wave 2 col-tiles from LDS ----
    for (int st = 0; st < TPC; ++st) {
      const int lcol = w * (CH / WAVES) + st * 16 + lr;   // 0..127 in chunk
      const int ctc  = cb + w * (CH / WAVES) + st * 16;   // tile base col
      const int colv = ctc + lr;
      short8 bfrag[4];
      for (int ks = 0; ks < 4; ++ks) {
        int ba = (lcol * 256 + ks * 64 + lg * 16) ^ ((lcol & 7) << 4);
        bfrag[ks] = *(const short8*)((char*)bsh + ba);
      }
      const int labc = lab_sh[lcol];

      for (int rt = 0; rt < RT; ++rt) {
        f32x4 acc = {0.f, 0.f, 0.f, 0.f};
        for (int ks = 0; ks < 4; ++ks)
          acc = __builtin_amdgcn_mfma_f32_16x16x32_bf16(afrag[rt][ks], bfrag[ks], acc, 0, 0, 0);
        const bool diag = (ctc == r0 + rt * 16);   // wave-uniform
        // C/D layout (verified): col = lane&15, row = (lane>>4)*4 + reg
        for (int rg = 0; rg < 4; ++rg) {
          int   i    = rt * 4 + rg;
          float s    = acc[rg];
          bool  eq   = (labc == labr[i]);
          bool  self = diag && (lr == lg * 4 + rg);
          if (PHASE == 0) {
            if (eq && !self) a0[i] = fminf(a0[i], s);
            if (!eq)         a1[i] = fmaxf(a1[i], s);
          } else {
            bool  kp   = eq && !self && (s < tp[i]);
            bool  kn   = (!eq) && (s > tn[i]);
            float argp = fmaf(s, -2.885390082f, 1.442695041f);   // -2*(s-0.5)*log2e
            float argn = fmaf(s, 57.70780163f, -28.85390082f);   // 40*(s-0.5)*log2e
            float e = exp2f(kp ? argp : argn);
            a0[i] += kp ? e : 0.f;
            a1[i] += kn ? e : 0.f;
          }
        }
      }
    }
    __syncthreads();   // chunk consumed before restage
  }

  // reduce across the 16 col-lanes sharing each row
  for (int i = 0; i < RT * 4; ++i) {
    for (int m = 1; m < 16; m <<= 1) {
      float o0 = __shfl_xor(a0[i], m, 64);
      float o1 = __shfl_xor(a1[i], m, 64);
      if (PHASE == 0) { a0[i] = fminf(a0[i], o0); a1[i] = fmaxf(a1[i], o1); }
      else            { a0[i] += o0;              a1[i] += o1; }
    }
  }
  if (lr == 0)
    for (int i = 0; i < RT * 4; ++i) {
      int rt = i >> 2, rg = i & 3;
      red[0][w][rt * 16 + lg * 4 + rg] = a0[i];
      red[1][w][rt * 16 + lg * 4 + rg] = a1[i];
    }
  __syncthreads();

  if (tid < RPB) {
    if (PHASE == 0) {
      float v0 = INFINITY, v1 = -INFINITY;
      for (int ww = 0; ww < WAVES; ++ww) {
        v0 = fminf(v0, red[0][ww][tid]);
        v1 = fmaxf(v1, red[1][ww][tid]);
      }
      out0[bx * Bsz + r0 + tid] = v0;
      out1[bx * Bsz + r0 + tid] = v1;
    } else {
      float v0 = 0.f, v1 = 0.f;
      for (int ww = 0; ww < WAVES; ++ww) {
        v0 += red[0][ww][tid];
        v1 += red[1][ww][tid];
      }
      out0[bx * Bsz + r0 + tid] = v0;
      out1[bx * Bsz + r0 + tid] = v1;
    }
  }
}

__global__ __launch_bounds__(1024)
void finalize(const float* __restrict__ pos_part, const float* __restrict__ neg_part,
              const float* __restrict__ vld, float* __restrict__ out) {
  int tid = threadIdx.x;
  float s = 0.f, c = 0.f;
  for (int r = tid; r < Bsz; r += 1024) {
    float ps = 0.f, ns = 0.f;
    for (int b = 0; b < COL_SPLIT; ++b) {
      ps += pos_part[b * Bsz + r];
      ns += neg_part[b * Bsz + r];
    }
    if (vld[r] > 0.f) {
      s += log1pf(ps) * 0.5f + log1pf(ns) * 0.025f;
      c += 1.f;
    }
  }
  for (int m = 1; m < 64; m <<= 1) {
    s += __shfl_xor(s, m, 64);
    c += __shfl_xor(c, m, 64);
  }
  __shared__ float rs[16], rc[16];
  int w = tid >> 6, lz = tid & 63;
  if (lz == 0) { rs[w] = s; rc[w] = c; }
  __syncthreads();
  if (tid == 0) {
    float ts = 0.f, tc = 0.f;
    for (int i = 0; i < 16; ++i) { ts += rs[i]; tc += rc[i]; }
    out[0] = ts / fmaxf(tc, 1.0f);
  }
}

extern "C" void kernel_launch(void* const* d_in, const int* in_sizes, int n_in,
                              void* d_out, int out_size, void* d_ws, size_t ws_size,
                              hipStream_t stream) {
  const float* X      = (const float*)d_in[0];
  const int*   labels = (const int*)d_in[1];

  char* ws = (char*)d_ws;
  short* Xb       = (short*)ws;                         // 1 MB
  float* min_part = (float*)(ws + 1048576);             // 128 KB
  float* max_part = (float*)(ws + 1048576 + 131072);    // 128 KB
  float* pos_part = (float*)(ws + 1048576 + 262144);    // 128 KB
  float* neg_part = (float*)(ws + 1048576 + 393216);    // 128 KB
  float* vld      = (float*)(ws + 1048576 + 524288);    // 16 KB

  convert_kernel<<<256, 256, 0, stream>>>(X, Xb);
  sweep<0><<<(Bsz / RPB) * COL_SPLIT, THREADS, 0, stream>>>(Xb, labels, nullptr, nullptr,
                                                            min_part, max_part, nullptr);
  sweep<1><<<(Bsz / RPB) * COL_SPLIT, THREADS, 0, stream>>>(Xb, labels, min_part, max_part,
                                                            pos_part, neg_part, vld);
  finalize<<<1, 1024, 0, stream>>>(pos_part, neg_part, vld, (float*)d_out);
}

// Round 11
// 47.288 us; speedup vs baseline: 6.2272x; 1.1651x over previous
//
#include <hip/hip_runtime.h>
#include <math.h>

#define Bsz 4096
#define Dk 128
#define RPB 32                   // rows per block
#define CS 16                    // column splits
#define CPB (Bsz / CS)           // 256 cols per block
#define THREADS 256
#define WAVES 4
#define CPW (CPB / WAVES)        // 64 cols per wave
#define CT (CPW / 16)            // 4 col-tiles per wave
#define RT (RPB / 16)            // 2 row-tiles

typedef __attribute__((ext_vector_type(8))) short short8;
typedef __attribute__((ext_vector_type(4))) float f32x4;

__device__ __forceinline__ unsigned short f2bf(float f) {
  unsigned u = __float_as_uint(f);
  u = (u + 0x7fffu + ((u >> 16) & 1u)) >> 16;   // RNE
  return (unsigned short)u;
}

// Xt layout: [kb][col][8] with kb = k/8 (16 x 4096 x 8 bf16).
// A wave's 16x16x32 fragment load becomes 4 x 256B contiguous segments
// (vs 16 x 64B in row-major) -> 4x fewer VMEM requests, no staging needed.
__global__ __launch_bounds__(256)
void convert_kernel(const float* __restrict__ X, short* __restrict__ Xt) {
  int i = blockIdx.x * 256 + threadIdx.x;     // 65536 = 4096 cols x 16 kb
  int col = i >> 4, kb = i & 15;
  const float4* q = (const float4*)(X + col * Dk + kb * 8);
  float4 v0 = q[0], v1 = q[1];
  short8 r;
  r[0] = (short)f2bf(v0.x); r[1] = (short)f2bf(v0.y);
  r[2] = (short)f2bf(v0.z); r[3] = (short)f2bf(v0.w);
  r[4] = (short)f2bf(v1.x); r[5] = (short)f2bf(v1.y);
  r[6] = (short)f2bf(v1.z); r[7] = (short)f2bf(v1.w);
  *(short8*)(Xt + (size_t)(kb * Bsz + col) * 8) = r;
}

// fragment element j of lane (lg,lr): X[col][ks*32 + lg*8 + j]
__device__ __forceinline__ short8 ldfrag(const short* __restrict__ Xt, int col, int ks, int lg) {
  return *(const short8*)(Xt + (size_t)(((ks << 2) + lg) * Bsz + col) * 8);
}

// Barrier-free GEMM sweep. PHASE 0: min(pos)/max(neg) partials.
// PHASE 1: thresholded exp-sum partials (+validity from bx==0).
template<int PHASE>
__global__ __launch_bounds__(THREADS, 4)
void sweep(const short* __restrict__ Xt, const int* __restrict__ labels,
           const float* __restrict__ min_part, const float* __restrict__ max_part,
           float* __restrict__ out0, float* __restrict__ out1,
           float* __restrict__ vld) {
  const int tid = threadIdx.x;
  const int w  = tid >> 6;
  const int l  = tid & 63;
  const int lg = l >> 4;     // k-group / C row-group
  const int lr = l & 15;     // A row-in-tile / B,C col-in-tile
  const int by = blockIdx.x / CS;
  const int bx = blockIdx.x % CS;
  const int r0 = by * RPB;
  const int c0 = bx * CPB + w * CPW;

  __shared__ float red[2][WAVES][RPB];
  __shared__ float thp_s[RPB], thn_s[RPB];

  if (PHASE == 1) {
    if (tid < RPB) {
      int r = r0 + tid;
      float mnr = INFINITY, mxr = -INFINITY;
#pragma unroll
      for (int b = 0; b < CS; ++b) {
        mnr = fminf(mnr, min_part[b * Bsz + r]);
        mxr = fmaxf(mxr, max_part[b * Bsz + r]);
      }
      thp_s[tid] = mxr + 0.1f;    // pos_keep: s < max_neg + 0.1
      thn_s[tid] = mnr - 0.1f;    // neg_keep: s > min_pos - 0.1
      if (bx == 0) vld[r] = (mnr - 0.1f < mxr) ? 1.0f : 0.0f;
    }
  }

  // A fragments: 32 rows x K=128 (coalesced 256B-segment loads from Xt)
  short8 afrag[RT][4];
  for (int rt = 0; rt < RT; ++rt)
    for (int ks = 0; ks < 4; ++ks)
      afrag[rt][ks] = ldfrag(Xt, r0 + rt * 16 + lr, ks, lg);

  int labr[RT * 4];
  for (int rt = 0; rt < RT; ++rt)
    for (int rg = 0; rg < 4; ++rg)
      labr[rt * 4 + rg] = labels[r0 + rt * 16 + lg * 4 + rg];

  float tp[RT * 4], tn[RT * 4];
  if (PHASE == 1) {
    __syncthreads();   // thp_s/thn_s ready (only barrier before epilogue)
    for (int rt = 0; rt < RT; ++rt)
      for (int rg = 0; rg < 4; ++rg) {
        int rl = rt * 16 + lg * 4 + rg;
        tp[rt * 4 + rg] = thp_s[rl];
        tn[rt * 4 + rg] = thn_s[rl];
      }
  }

  float a0[RT * 4], a1[RT * 4];
  for (int i = 0; i < RT * 4; ++i) {
    a0[i] = (PHASE == 0) ? INFINITY  : 0.f;
    a1[i] = (PHASE == 0) ? -INFINITY : 0.f;
  }

#pragma unroll
  for (int ct = 0; ct < CT; ++ct) {
    const int ctc  = c0 + ct * 16;
    const int colv = ctc + lr;
    short8 bfrag[4];
    for (int ks = 0; ks < 4; ++ks) bfrag[ks] = ldfrag(Xt, colv, ks, lg);
    const int labc = labels[colv];

    for (int rt = 0; rt < RT; ++rt) {
      f32x4 acc = {0.f, 0.f, 0.f, 0.f};
      for (int ks = 0; ks < 4; ++ks)
        acc = __builtin_amdgcn_mfma_f32_16x16x32_bf16(afrag[rt][ks], bfrag[ks], acc, 0, 0, 0);
      const bool diag = (ctc == r0 + rt * 16);   // wave-uniform
      // C/D layout (verified): col = lane&15, row = (lane>>4)*4 + reg
      for (int rg = 0; rg < 4; ++rg) {
        int   i    = rt * 4 + rg;
        float s    = acc[rg];
        bool  eq   = (labc == labr[i]);
        bool  self = diag && (lr == lg * 4 + rg);
        if (PHASE == 0) {
          if (eq && !self) a0[i] = fminf(a0[i], s);
          if (!eq)         a1[i] = fmaxf(a1[i], s);
        } else {
          bool  kp   = eq && !self && (s < tp[i]);
          bool  kn   = (!eq) && (s > tn[i]);
          float argp = fmaf(s, -2.885390082f, 1.442695041f);   // -2*(s-0.5)*log2e
          float argn = fmaf(s, 57.70780163f, -28.85390082f);   // 40*(s-0.5)*log2e
          float e = exp2f(kp ? argp : argn);
          a0[i] += kp ? e : 0.f;
          a1[i] += kn ? e : 0.f;
        }
      }
    }
  }

  // reduce across the 16 col-lanes sharing each row
  for (int i = 0; i < RT * 4; ++i) {
    for (int m = 1; m < 16; m <<= 1) {
      float o0 = __shfl_xor(a0[i], m, 64);
      float o1 = __shfl_xor(a1[i], m, 64);
      if (PHASE == 0) { a0[i] = fminf(a0[i], o0); a1[i] = fmaxf(a1[i], o1); }
      else            { a0[i] += o0;              a1[i] += o1; }
    }
  }
  if (lr == 0)
    for (int i = 0; i < RT * 4; ++i) {
      int rt = i >> 2, rg = i & 3;
      red[0][w][rt * 16 + lg * 4 + rg] = a0[i];
      red[1][w][rt * 16 + lg * 4 + rg] = a1[i];
    }
  __syncthreads();

  if (tid < RPB) {
    if (PHASE == 0) {
      float v0 = INFINITY, v1 = -INFINITY;
      for (int ww = 0; ww < WAVES; ++ww) {
        v0 = fminf(v0, red[0][ww][tid]);
        v1 = fmaxf(v1, red[1][ww][tid]);
      }
      out0[bx * Bsz + r0 + tid] = v0;
      out1[bx * Bsz + r0 + tid] = v1;
    } else {
      float v0 = 0.f, v1 = 0.f;
      for (int ww = 0; ww < WAVES; ++ww) {
        v0 += red[0][ww][tid];
        v1 += red[1][ww][tid];
      }
      out0[bx * Bsz + r0 + tid] = v0;
      out1[bx * Bsz + r0 + tid] = v1;
    }
  }
}

__global__ __launch_bounds__(1024)
void finalize(const float* __restrict__ pos_part, const float* __restrict__ neg_part,
              const float* __restrict__ vld, float* __restrict__ out) {
  int tid = threadIdx.x;
  float s = 0.f, c = 0.f;
  for (int r = tid; r < Bsz; r += 1024) {
    float ps = 0.f, ns = 0.f;
#pragma unroll
    for (int b = 0; b < CS; ++b) {
      ps += pos_part[b * Bsz + r];
      ns += neg_part[b * Bsz + r];
    }
    if (vld[r] > 0.f) {
      s += log1pf(ps) * 0.5f + log1pf(ns) * 0.025f;
      c += 1.f;
    }
  }
  for (int m = 1; m < 64; m <<= 1) {
    s += __shfl_xor(s, m, 64);
    c += __shfl_xor(c, m, 64);
  }
  __shared__ float rs[16], rc[16];
  int w = tid >> 6, lz = tid & 63;
  if (lz == 0) { rs[w] = s; rc[w] = c; }
  __syncthreads();
  if (tid == 0) {
    float ts = 0.f, tc = 0.f;
    for (int i = 0; i < 16; ++i) { ts += rs[i]; tc += rc[i]; }
    out[0] = ts / fmaxf(tc, 1.0f);
  }
}

extern "C" void kernel_launch(void* const* d_in, const int* in_sizes, int n_in,
                              void* d_out, int out_size, void* d_ws, size_t ws_size,
                              hipStream_t stream) {
  const float* X      = (const float*)d_in[0];
  const int*   labels = (const int*)d_in[1];

  char* ws = (char*)d_ws;
  short* Xt       = (short*)ws;                          // 1 MB (k-block transposed)
  float* min_part = (float*)(ws + 1048576);              // 256 KB (16 x 4096)
  float* max_part = (float*)(ws + 1048576 + 262144);     // 256 KB
  float* pos_part = (float*)(ws + 1048576 + 524288);     // 256 KB
  float* neg_part = (float*)(ws + 1048576 + 786432);     // 256 KB
  float* vld      = (float*)(ws + 2097152);              // 16 KB

  convert_kernel<<<256, 256, 0, stream>>>(X, Xt);
  sweep<0><<<(Bsz / RPB) * CS, THREADS, 0, stream>>>(Xt, labels, nullptr, nullptr,
                                                     min_part, max_part, nullptr);
  sweep<1><<<(Bsz / RPB) * CS, THREADS, 0, stream>>>(Xt, labels, min_part, max_part,
                                                     pos_part, neg_part, vld);
  finalize<<<1, 1024, 0, stream>>>(pos_part, neg_part, vld, (float*)d_out);
}